// Round 1
// baseline (942.668 us; speedup 1.0000x reference)
//
#include <hip/hip_runtime.h>
#include <math.h>

#define LMAXX 6
#define SH49 49
#define TPB 256
#define TILE_E 64

// ---------------------------------------------------------------------------
// Real spherical harmonics up to l=6, 'component' normalization.
// All array indices are static after unrolling -> stays in registers when
// `sh` is a local array; writes straight to global when given a global ptr.
// ---------------------------------------------------------------------------
__device__ __forceinline__ void sph49(float x, float y, float z, float* sh) {
    float nn = sqrtf(x * x + y * y + z * z + 1e-12f);
    float iv = 1.0f / nn;
    x *= iv; y *= iv; z *= iv;
    float st2 = x * x + y * y;
    float st = sqrtf(st2 > 0.f ? st2 : 0.f);
    float cphi, sphi;
    if (st > 1e-30f) { cphi = x / st; sphi = y / st; }
    else { cphi = 1.0f; sphi = 0.0f; }

    float P[LMAXX + 1][LMAXX + 1];
    P[0][0] = 0.28209479177387814f;   // sqrt(1/4pi)
#pragma unroll
    for (int m = 1; m <= LMAXX; ++m)
        P[m][m] = -sqrtf((2.f * m + 1.f) / (2.f * m)) * st * P[m - 1][m - 1];
#pragma unroll
    for (int m = 0; m < LMAXX; ++m)
        P[m + 1][m] = sqrtf(2.f * m + 3.f) * z * P[m][m];
#pragma unroll
    for (int m = 0; m <= LMAXX; ++m) {
#pragma unroll
        for (int l = m + 2; l <= LMAXX; ++l) {
            float a = sqrtf((4.f * l * l - 1.f) / (float)(l * l - m * m));
            float b = sqrtf((float)((l - 1) * (l - 1) - m * m) /
                            (4.f * (l - 1) * (l - 1) - 1.f));
            P[l][m] = a * (z * P[l - 1][m] - b * P[l - 2][m]);
        }
    }
    float cm[LMAXX + 1], sm[LMAXX + 1];
    cm[0] = 1.f; sm[0] = 0.f; cm[1] = cphi; sm[1] = sphi;
#pragma unroll
    for (int m = 2; m <= LMAXX; ++m) {
        cm[m] = 2.f * cphi * cm[m - 1] - cm[m - 2];
        sm[m] = 2.f * cphi * sm[m - 1] - sm[m - 2];
    }
    const float s4pi = 3.5449077018110318f;      // sqrt(4pi)
    const float s8pi = 5.0132565492620005f;      // sqrt(4pi)*sqrt(2)
    int idx = 0;
#pragma unroll
    for (int l = 0; l <= LMAXX; ++l) {
#pragma unroll
        for (int mm = -l; mm <= l; ++mm) {
            if (mm < 0)       sh[idx++] = s8pi * P[l][-mm] * sm[-mm];
            else if (mm == 0) sh[idx++] = s4pi * P[l][0];
            else              sh[idx++] = s8pi * P[l][mm] * cm[mm];
        }
    }
}

// ---------------------------------------------------------------------------
// K1: accumulate per-destination-node udiff sum + counts (atomics).
// edge_index layout: row0 = j (source), row1 = i (dest).
// ---------------------------------------------------------------------------
__global__ void k_scatter_ref(const float* __restrict__ ud,
                              const int* __restrict__ eidx,
                              float* __restrict__ acc, float* __restrict__ cnt,
                              int E) {
    int e = blockIdx.x * blockDim.x + threadIdx.x;
    if (e >= E) return;
    int i = eidx[E + e];
    atomicAdd(&acc[3 * i + 0], ud[3 * e + 0]);
    atomicAdd(&acc[3 * i + 1], ud[3 * e + 1]);
    atomicAdd(&acc[3 * i + 2], ud[3 * e + 2]);
    atomicAdd(&cnt[i], 1.0f);
}

// ---------------------------------------------------------------------------
// K2: per-node ref_vec normalize + zero-mask + ref spherical harmonics.
// ---------------------------------------------------------------------------
__global__ void k_node_ref(const float* __restrict__ acc,
                           const float* __restrict__ cnt,
                           float* __restrict__ ref_vec,
                           float* __restrict__ ref_sh, int N) {
    int n = blockIdx.x * blockDim.x + threadIdx.x;
    if (n >= N) return;
    float c = cnt[n];
    float d = fmaxf(c, 1.0f);
    float vx = acc[3 * n + 0] / d;
    float vy = acc[3 * n + 1] / d;
    float vz = acc[3 * n + 2] / d;
    float norm = sqrtf(vx * vx + vy * vy + vz * vz + 1e-9f);
    float ivn = 1.0f / norm;
    vx *= ivn; vy *= ivn; vz *= ivn;
    if (norm < 5e-5f) { vx = 1.f; vy = 0.f; vz = 0.f; }
    ref_vec[3 * n + 0] = vx;
    ref_vec[3 * n + 1] = vy;
    ref_vec[3 * n + 2] = vz;
    sph49(vx, vy, vz, ref_sh + (size_t)n * SH49);
}

// ---------------------------------------------------------------------------
// K3: scalar_proj = scaled_silu(ns @ W1 + b1) @ W2 + b2   (N x 192)
// One wave per node; weights staged in LDS.
// ---------------------------------------------------------------------------
__global__ __launch_bounds__(TPB) void k_sproj(const float* __restrict__ ns,
                                               const float* __restrict__ W1,
                                               const float* __restrict__ b1,
                                               const float* __restrict__ W2,
                                               const float* __restrict__ b2,
                                               float* __restrict__ sproj, int N) {
    __shared__ float sW1[64 * 32];
    __shared__ float sW2[32 * 192];
    __shared__ float sb2[192];
    __shared__ float sb1[32];
    __shared__ float sbuf[4][64];
    __shared__ float h1buf[4][32];
    int t = threadIdx.x;
    for (int p = t; p < 64 * 32; p += TPB) sW1[p] = W1[p];
    for (int p = t; p < 32 * 192; p += TPB) sW2[p] = W2[p];
    if (t < 192) sb2[t] = b2[t];
    if (t < 32) sb1[t] = b1[t];

    int w = t >> 6, l = t & 63;
    int nwaves = gridDim.x * 4;
    int iters = (N + nwaves - 1) / nwaves;
    for (int it = 0; it < iters; ++it) {
        int n = blockIdx.x * 4 + w + it * nwaves;
        bool act = n < N;
        __syncthreads();
        if (act) sbuf[w][l] = ns[(size_t)n * 64 + l];
        __syncthreads();
        float h = 0.f;
        if (act) {
            int k = l & 31;
            h = sb1[k];
#pragma unroll
            for (int c = 0; c < 64; ++c) h = fmaf(sbuf[w][c], sW1[c * 32 + k], h);
            float sig = 1.0f / (1.0f + __expf(-h));
            h = h * sig * (1.0f / 0.6f);
            if (l < 32) h1buf[w][l] = h;
        }
        __syncthreads();
        if (act) {
#pragma unroll
            for (int m = 0; m < 3; ++m) {
                int o = l + 64 * m;
                float a = sb2[o];
#pragma unroll
                for (int kk = 0; kk < 32; ++kk)
                    a = fmaf(h1buf[w][kk], sW2[kk * 192 + o], a);
                sproj[(size_t)n * 192 + o] = a;
            }
        }
    }
}

// ---------------------------------------------------------------------------
// K4: per-edge geometry features: edge SH x ref SH invariants -> LN -> geom[8]
// ---------------------------------------------------------------------------
__global__ void k_geom(const float* __restrict__ ud, const int* __restrict__ eidx,
                       const float* __restrict__ ref_vec,
                       const float* __restrict__ ref_sh,
                       const float* __restrict__ ln_g, const float* __restrict__ ln_b,
                       float* __restrict__ geom, int E) {
    int e = blockIdx.x * blockDim.x + threadIdx.x;
    if (e >= E) return;
    int i = eidx[E + e];
    float ux = ud[3 * e], uy = ud[3 * e + 1], uz = ud[3 * e + 2];
    float esh[SH49];
    sph49(ux, uy, uz, esh);
    const float* rs = ref_sh + (size_t)i * SH49;
    float inv[7];
    int idx = 0;
#pragma unroll
    for (int l = 0; l <= 6; ++l) {
        float s = 0.f;
#pragma unroll
        for (int m = 0; m < 2 * l + 1; ++m) { s += esh[idx] * rs[idx]; idx++; }
        inv[l] = s / (float)(2 * l + 1);
    }
    float mu = 0.f;
#pragma unroll
    for (int l = 0; l < 7; ++l) mu += inv[l];
    mu *= (1.0f / 7.0f);
    float var = 0.f;
#pragma unroll
    for (int l = 0; l < 7; ++l) { float d = inv[l] - mu; var += d * d; }
    var *= (1.0f / 7.0f);
    float rstd = rsqrtf(var + 1e-5f);
    float rvx = ref_vec[3 * i], rvy = ref_vec[3 * i + 1], rvz = ref_vec[3 * i + 2];
    float ct = ux * rvx + uy * rvy + uz * rvz;
    float* g = geom + (size_t)e * 8;
    g[0] = ct;
#pragma unroll
    for (int l = 0; l < 7; ++l) g[1 + l] = (inv[l] - mu) * rstd * ln_g[l] + ln_b[l];
}

// ---------------------------------------------------------------------------
// K5: fused main kernel.
//   rbf_h = rbf @ W_edge + b_edge          (tiled fp32 GEMM, W in LDS)
//   gate  = tanh(scaled_silu(geom @ W_inv + b_inv))
//   x     = sproj[j] * rbf_h * (1+gate) / sqrt(3)
//   scatter x3 -> delta_scalar[i];  (x1*nv[j] + x2*ud)/sqrt(H) -> delta_vector[i]
// Thread t: oc = t&31 -> output cols {oc+32m, m=0..5}; er = t>>5 -> 8 edges.
// ---------------------------------------------------------------------------
__global__ __launch_bounds__(TPB, 2) void k_main(
    const float* __restrict__ rbf, const float* __restrict__ W_edge,
    const float* __restrict__ b_edge, const float* __restrict__ W_inv,
    const float* __restrict__ b_inv, const float* __restrict__ geom,
    const float* __restrict__ sproj, const float* __restrict__ nvec,
    const float* __restrict__ ud, const int* __restrict__ eidx,
    float* __restrict__ dscal, float* __restrict__ dvec, int E) {
    __shared__ float sW[64 * 192];
    __shared__ float sWinv[8 * 192];
    __shared__ float sbe[192];
    __shared__ float sbi[192];
    __shared__ float rbfT[64 * 68];   // [k][edge], pad 68 keeps 16B align + breaks conflicts
    __shared__ float sgeom[64 * 8];
    __shared__ float sud[64 * 3];
    __shared__ int sii[64];
    __shared__ int sjj[64];

    int t = threadIdx.x;
    for (int p = t; p < 64 * 192; p += TPB) sW[p] = W_edge[p];
    for (int p = t; p < 8 * 192; p += TPB) sWinv[p] = W_inv[p];
    if (t < 192) { sbe[t] = b_edge[t]; sbi[t] = b_inv[t]; }

    int oc = t & 31;
    int er = t >> 5;  // 0..7
    const float inv_sqrt3 = 0.57735026918962584f;
    const float inv_sqrt_h = 0.125f;

    int ntiles = (E + TILE_E - 1) / TILE_E;
    for (int tile = blockIdx.x; tile < ntiles; tile += gridDim.x) {
        int e0 = tile * TILE_E;
        __syncthreads();   // previous epilogue done before restage
        if (t < 64) {
            int eg = e0 + t;
            sjj[t] = (eg < E) ? eidx[eg] : 0;
            sii[t] = (eg < E) ? eidx[E + eg] : 0;
        }
        for (int p = t; p < 64 * 8; p += TPB)
            sgeom[p] = (e0 + (p >> 3) < E) ? geom[(size_t)e0 * 8 + p] : 0.f;
        for (int p = t; p < 64 * 3; p += TPB)
            sud[p] = (e0 + p / 3 < E) ? ud[(size_t)e0 * 3 + p] : 0.f;
        {
            int w = t >> 6, l = t & 63;
#pragma unroll
            for (int p = 0; p < 16; ++p) {
                int r = w + 4 * p;
                int eg = e0 + r;
                float v = (eg < E) ? rbf[(size_t)eg * 64 + l] : 0.f;
                rbfT[l * 68 + r] = v;
            }
        }
        __syncthreads();

        float acc[8][6];
#pragma unroll
        for (int e = 0; e < 8; ++e)
#pragma unroll
            for (int m = 0; m < 6; ++m) acc[e][m] = 0.f;

        const float* rb = &rbfT[er * 8];
#pragma unroll 4
        for (int k = 0; k < 64; ++k) {
            float4 r0 = *(const float4*)&rb[k * 68];
            float4 r1 = *(const float4*)&rb[k * 68 + 4];
            float wv[6];
#pragma unroll
            for (int m = 0; m < 6; ++m) wv[m] = sW[k * 192 + oc + 32 * m];
            float re[8] = {r0.x, r0.y, r0.z, r0.w, r1.x, r1.y, r1.z, r1.w};
#pragma unroll
            for (int e = 0; e < 8; ++e)
#pragma unroll
                for (int m = 0; m < 6; ++m)
                    acc[e][m] = fmaf(re[e], wv[m], acc[e][m]);
        }

#pragma unroll 1
        for (int e = 0; e < 8; ++e) {
            int el = er * 8 + e;
            int eg = e0 + el;
            if (eg >= E) continue;
            int j = sjj[el], i = sii[el];
            float x[6];
#pragma unroll
            for (int m = 0; m < 6; ++m) {
                int o = oc + 32 * m;
                float u = sbi[o];
#pragma unroll
                for (int c = 0; c < 8; ++c)
                    u = fmaf(sgeom[el * 8 + c], sWinv[c * 192 + o], u);
                float sig = 1.0f / (1.0f + __expf(-u));
                float v = u * sig * (1.0f / 0.6f);
                v = fminf(fmaxf(v, -20.f), 20.f);
                float e2v = __expf(2.0f * v);
                float gate = (e2v - 1.0f) / (e2v + 1.0f);
                float rh = (acc[e][m] + sbe[o]) * (1.0f + gate);
                x[m] = sproj[(size_t)j * 192 + o] * rh * inv_sqrt3;
            }
            atomicAdd(&dscal[(size_t)i * 64 + oc], x[4]);
            atomicAdd(&dscal[(size_t)i * 64 + oc + 32], x[5]);
            float udv[3] = {sud[el * 3], sud[el * 3 + 1], sud[el * 3 + 2]};
            const float* nv = &nvec[(size_t)j * 192];
#pragma unroll
            for (int d = 0; d < 3; ++d) {
                float v1 = (x[0] * nv[d * 64 + oc] + x[2] * udv[d]) * inv_sqrt_h;
                float v2 = (x[1] * nv[d * 64 + oc + 32] + x[3] * udv[d]) * inv_sqrt_h;
                atomicAdd(&dvec[(size_t)i * 192 + d * 64 + oc], v1);
                atomicAdd(&dvec[(size_t)i * 192 + d * 64 + oc + 32], v2);
            }
        }
    }
}

// ---------------------------------------------------------------------------
extern "C" void kernel_launch(void* const* d_in, const int* in_sizes, int n_in,
                              void* d_out, int out_size, void* d_ws, size_t ws_size,
                              hipStream_t stream) {
    const float* node_scalar = (const float*)d_in[0];
    const float* node_vector = (const float*)d_in[1];
    const float* edge_rbf    = (const float*)d_in[2];
    const float* edge_udiff  = (const float*)d_in[3];
    const int*   edge_index  = (const int*)d_in[4];
    const float* W_edge      = (const float*)d_in[5];
    const float* b_edge      = (const float*)d_in[6];
    const float* W_x1        = (const float*)d_in[7];
    const float* b_x1        = (const float*)d_in[8];
    const float* W_x2        = (const float*)d_in[9];
    const float* b_x2        = (const float*)d_in[10];
    const float* ln_g        = (const float*)d_in[11];
    const float* ln_b        = (const float*)d_in[12];
    const float* W_inv       = (const float*)d_in[13];
    const float* b_inv       = (const float*)d_in[14];

    int N = in_sizes[0] / 64;
    int E = in_sizes[3] / 3;

    float* ws      = (float*)d_ws;
    float* ref_acc = ws;                      // N*3
    float* cnt     = ws + (size_t)N * 3;      // N
    float* ref_vec = ws + (size_t)N * 4;      // N*3
    float* ref_sh  = ws + (size_t)N * 7;      // N*49
    float* sproj   = ws + (size_t)N * 56;     // N*192
    float* geom    = ws + (size_t)N * 248;    // E*8

    float* dscal = (float*)d_out;                       // N*64
    float* dvec  = (float*)d_out + (size_t)N * 64;      // N*192

    hipMemsetAsync(ref_acc, 0, (size_t)N * 4 * sizeof(float), stream);
    hipMemsetAsync(d_out, 0, (size_t)out_size * sizeof(float), stream);

    k_scatter_ref<<<(E + TPB - 1) / TPB, TPB, 0, stream>>>(edge_udiff, edge_index,
                                                           ref_acc, cnt, E);
    k_node_ref<<<(N + TPB - 1) / TPB, TPB, 0, stream>>>(ref_acc, cnt, ref_vec,
                                                        ref_sh, N);
    k_sproj<<<512, TPB, 0, stream>>>(node_scalar, W_x1, b_x1, W_x2, b_x2, sproj, N);
    k_geom<<<(E + TPB - 1) / TPB, TPB, 0, stream>>>(edge_udiff, edge_index, ref_vec,
                                                    ref_sh, ln_g, ln_b, geom, E);
    k_main<<<512, TPB, 0, stream>>>(edge_rbf, W_edge, b_edge, W_inv, b_inv, geom,
                                    sproj, node_vector, edge_udiff, edge_index,
                                    dscal, dvec, E);
}

// Round 2
// 885.768 us; speedup vs baseline: 1.0642x; 1.0642x over previous
//
#include <hip/hip_runtime.h>
#include <math.h>

#define LMAXX 6
#define SH49 49
#define TPB 256
#define TILE_E 64
#define SCB 256

// ---------------------------------------------------------------------------
// Real spherical harmonics up to l=6, 'component' normalization.
// ---------------------------------------------------------------------------
__device__ __forceinline__ void sph49(float x, float y, float z, float* sh) {
    float nn = sqrtf(x * x + y * y + z * z + 1e-12f);
    float iv = 1.0f / nn;
    x *= iv; y *= iv; z *= iv;
    float st2 = x * x + y * y;
    float st = sqrtf(st2 > 0.f ? st2 : 0.f);
    float cphi, sphi;
    if (st > 1e-30f) { cphi = x / st; sphi = y / st; }
    else { cphi = 1.0f; sphi = 0.0f; }

    float P[LMAXX + 1][LMAXX + 1];
    P[0][0] = 0.28209479177387814f;   // sqrt(1/4pi)
#pragma unroll
    for (int m = 1; m <= LMAXX; ++m)
        P[m][m] = -sqrtf((2.f * m + 1.f) / (2.f * m)) * st * P[m - 1][m - 1];
#pragma unroll
    for (int m = 0; m < LMAXX; ++m)
        P[m + 1][m] = sqrtf(2.f * m + 3.f) * z * P[m][m];
#pragma unroll
    for (int m = 0; m <= LMAXX; ++m) {
#pragma unroll
        for (int l = m + 2; l <= LMAXX; ++l) {
            float a = sqrtf((4.f * l * l - 1.f) / (float)(l * l - m * m));
            float b = sqrtf((float)((l - 1) * (l - 1) - m * m) /
                            (4.f * (l - 1) * (l - 1) - 1.f));
            P[l][m] = a * (z * P[l - 1][m] - b * P[l - 2][m]);
        }
    }
    float cm[LMAXX + 1], sm[LMAXX + 1];
    cm[0] = 1.f; sm[0] = 0.f; cm[1] = cphi; sm[1] = sphi;
#pragma unroll
    for (int m = 2; m <= LMAXX; ++m) {
        cm[m] = 2.f * cphi * cm[m - 1] - cm[m - 2];
        sm[m] = 2.f * cphi * sm[m - 1] - sm[m - 2];
    }
    const float s4pi = 3.5449077018110318f;      // sqrt(4pi)
    const float s8pi = 5.0132565492620005f;      // sqrt(4pi)*sqrt(2)
    int idx = 0;
#pragma unroll
    for (int l = 0; l <= LMAXX; ++l) {
#pragma unroll
        for (int mm = -l; mm <= l; ++mm) {
            if (mm < 0)       sh[idx++] = s8pi * P[l][-mm] * sm[-mm];
            else if (mm == 0) sh[idx++] = s4pi * P[l][0];
            else              sh[idx++] = s8pi * P[l][mm] * cm[mm];
        }
    }
}

// ---------------------------------------------------------------------------
// K1: per-destination udiff sum (float atomics) + integer degree histogram.
// ---------------------------------------------------------------------------
__global__ void k_scatter_ref(const float* __restrict__ ud,
                              const int* __restrict__ eidx,
                              float* __restrict__ acc, int* __restrict__ icnt,
                              int E) {
    int e = blockIdx.x * blockDim.x + threadIdx.x;
    if (e >= E) return;
    int i = eidx[E + e];
    atomicAdd(&acc[3 * i + 0], ud[3 * e + 0]);
    atomicAdd(&acc[3 * i + 1], ud[3 * e + 1]);
    atomicAdd(&acc[3 * i + 2], ud[3 * e + 2]);
    atomicAdd(&icnt[i], 1);
}

// ---------------------------------------------------------------------------
// K2: per-node ref_vec normalize + zero-mask + ref spherical harmonics.
// ---------------------------------------------------------------------------
__global__ void k_node_ref(const float* __restrict__ acc,
                           const int* __restrict__ icnt,
                           float* __restrict__ ref_vec,
                           float* __restrict__ ref_sh, int N) {
    int n = blockIdx.x * blockDim.x + threadIdx.x;
    if (n >= N) return;
    float c = (float)icnt[n];
    float d = fmaxf(c, 1.0f);
    float vx = acc[3 * n + 0] / d;
    float vy = acc[3 * n + 1] / d;
    float vz = acc[3 * n + 2] / d;
    float norm = sqrtf(vx * vx + vy * vy + vz * vz + 1e-9f);
    float ivn = 1.0f / norm;
    vx *= ivn; vy *= ivn; vz *= ivn;
    if (norm < 5e-5f) { vx = 1.f; vy = 0.f; vz = 0.f; }
    ref_vec[3 * n + 0] = vx;
    ref_vec[3 * n + 1] = vy;
    ref_vec[3 * n + 2] = vz;
    sph49(vx, vy, vz, ref_sh + (size_t)n * SH49);
}

// ---------------------------------------------------------------------------
// Counting-sort scan kernels: exclusive prefix over icnt[N].
// ---------------------------------------------------------------------------
__global__ void k_scan1(const int* __restrict__ icnt, int* __restrict__ offs,
                        int* __restrict__ bsum, int N) {
    __shared__ int s[SCB];
    int t = threadIdx.x;
    int idx = blockIdx.x * SCB + t;
    int v = (idx < N) ? icnt[idx] : 0;
    s[t] = v; __syncthreads();
#pragma unroll
    for (int off = 1; off < SCB; off <<= 1) {
        int u = (t >= off) ? s[t - off] : 0;
        __syncthreads();
        s[t] += u;
        __syncthreads();
    }
    if (idx < N) offs[idx] = s[t] - v;          // exclusive
    if (t == SCB - 1) bsum[blockIdx.x] = s[t];  // block total
}

__global__ void k_scan2(int* __restrict__ bsum, int nb) {
    __shared__ int s[1024];
    int t = threadIdx.x;
    int v = (t < nb) ? bsum[t] : 0;
    s[t] = v; __syncthreads();
#pragma unroll
    for (int off = 1; off < 1024; off <<= 1) {
        int u = (t >= off) ? s[t - off] : 0;
        __syncthreads();
        s[t] += u;
        __syncthreads();
    }
    if (t < nb) bsum[t] = s[t] - v;             // exclusive
}

__global__ void k_scan3(int* __restrict__ offs, const int* __restrict__ bsum,
                        int* __restrict__ cursor, int N) {
    int idx = blockIdx.x * SCB + threadIdx.x;
    if (idx >= N) return;
    int o = offs[idx] + bsum[blockIdx.x];
    offs[idx] = o;
    cursor[idx] = o;
}

__global__ void k_perm(const int* __restrict__ eidx, int* __restrict__ cursor,
                       int* __restrict__ perm, int E) {
    int e = blockIdx.x * blockDim.x + threadIdx.x;
    if (e >= E) return;
    int i = eidx[E + e];
    int pos = atomicAdd(&cursor[i], 1);
    perm[pos] = e;
}

// ---------------------------------------------------------------------------
// K3: scalar_proj = scaled_silu(ns @ W1 + b1) @ W2 + b2   (N x 192)
// ---------------------------------------------------------------------------
__global__ __launch_bounds__(TPB) void k_sproj(const float* __restrict__ ns,
                                               const float* __restrict__ W1,
                                               const float* __restrict__ b1,
                                               const float* __restrict__ W2,
                                               const float* __restrict__ b2,
                                               float* __restrict__ sproj, int N) {
    __shared__ float sW1[64 * 32];
    __shared__ float sW2[32 * 192];
    __shared__ float sb2[192];
    __shared__ float sb1[32];
    __shared__ float sbuf[4][64];
    __shared__ float h1buf[4][32];
    int t = threadIdx.x;
    for (int p = t; p < 64 * 32; p += TPB) sW1[p] = W1[p];
    for (int p = t; p < 32 * 192; p += TPB) sW2[p] = W2[p];
    if (t < 192) sb2[t] = b2[t];
    if (t < 32) sb1[t] = b1[t];

    int w = t >> 6, l = t & 63;
    int nwaves = gridDim.x * 4;
    int iters = (N + nwaves - 1) / nwaves;
    for (int it = 0; it < iters; ++it) {
        int n = blockIdx.x * 4 + w + it * nwaves;
        bool act = n < N;
        __syncthreads();
        if (act) sbuf[w][l] = ns[(size_t)n * 64 + l];
        __syncthreads();
        float h = 0.f;
        if (act) {
            int k = l & 31;
            h = sb1[k];
#pragma unroll
            for (int c = 0; c < 64; ++c) h = fmaf(sbuf[w][c], sW1[c * 32 + k], h);
            float sig = 1.0f / (1.0f + __expf(-h));
            h = h * sig * (1.0f / 0.6f);
            if (l < 32) h1buf[w][l] = h;
        }
        __syncthreads();
        if (act) {
#pragma unroll
            for (int m = 0; m < 3; ++m) {
                int o = l + 64 * m;
                float a = sb2[o];
#pragma unroll
                for (int kk = 0; kk < 32; ++kk)
                    a = fmaf(h1buf[w][kk], sW2[kk * 192 + o], a);
                sproj[(size_t)n * 192 + o] = a;
            }
        }
    }
}

// ---------------------------------------------------------------------------
// K4: geometry features in SORTED edge order. r = sorted rank, e = perm[r].
// Emits geom_s/ud_s/ii_s/jj_s coalesced in sorted layout for k_main.
// ---------------------------------------------------------------------------
__global__ void k_geom_s(const int* __restrict__ perm,
                         const float* __restrict__ ud, const int* __restrict__ eidx,
                         const float* __restrict__ ref_vec,
                         const float* __restrict__ ref_sh,
                         const float* __restrict__ ln_g, const float* __restrict__ ln_b,
                         float* __restrict__ geom_s, float* __restrict__ ud_s,
                         int* __restrict__ ii_s, int* __restrict__ jj_s, int E) {
    int r = blockIdx.x * blockDim.x + threadIdx.x;
    if (r >= E) return;
    int e = perm[r];
    int i = eidx[E + e];
    int j = eidx[e];
    float ux = ud[3 * e], uy = ud[3 * e + 1], uz = ud[3 * e + 2];
    float esh[SH49];
    sph49(ux, uy, uz, esh);
    const float* rs = ref_sh + (size_t)i * SH49;
    float inv[7];
    int idx = 0;
#pragma unroll
    for (int l = 0; l <= 6; ++l) {
        float s = 0.f;
#pragma unroll
        for (int m = 0; m < 2 * l + 1; ++m) { s += esh[idx] * rs[idx]; idx++; }
        inv[l] = s / (float)(2 * l + 1);
    }
    float mu = 0.f;
#pragma unroll
    for (int l = 0; l < 7; ++l) mu += inv[l];
    mu *= (1.0f / 7.0f);
    float var = 0.f;
#pragma unroll
    for (int l = 0; l < 7; ++l) { float d = inv[l] - mu; var += d * d; }
    var *= (1.0f / 7.0f);
    float rstd = rsqrtf(var + 1e-5f);
    float rvx = ref_vec[3 * i], rvy = ref_vec[3 * i + 1], rvz = ref_vec[3 * i + 2];
    float ct = ux * rvx + uy * rvy + uz * rvz;
    float* g = geom_s + (size_t)r * 8;
    g[0] = ct;
#pragma unroll
    for (int l = 0; l < 7; ++l) g[1 + l] = (inv[l] - mu) * rstd * ln_g[l] + ln_b[l];
    ud_s[3 * r + 0] = ux;
    ud_s[3 * r + 1] = uy;
    ud_s[3 * r + 2] = uz;
    ii_s[r] = i;
    jj_s[r] = j;
}

// ---------------------------------------------------------------------------
// K5: fused main kernel over SORTED edges.
//   rbf_h = rbf[perm] @ W_edge + b_edge   (tiled fp32 GEMM, W in LDS)
//   gate  = tanh(scaled_silu(geom @ W_inv + b_inv))
//   x     = sproj[j] * rbf_h * (1+gate) / sqrt(3)
// Epilogue: per-thread run accumulation over consecutive same-i edges, one
// atomic flush per run (edges sorted by i -> ~4-5x fewer atomics).
// ---------------------------------------------------------------------------
__global__ __launch_bounds__(TPB, 2) void k_main(
    const float* __restrict__ rbf, const float* __restrict__ W_edge,
    const float* __restrict__ b_edge, const float* __restrict__ W_inv,
    const float* __restrict__ b_inv, const float* __restrict__ geom_s,
    const float* __restrict__ sproj, const float* __restrict__ nvec,
    const float* __restrict__ ud_s, const int* __restrict__ ii_s,
    const int* __restrict__ jj_s, const int* __restrict__ perm,
    float* __restrict__ dscal, float* __restrict__ dvec, int E) {
    __shared__ float sW[64 * 192];
    __shared__ float sWinv[8 * 192];
    __shared__ float sbe[192];
    __shared__ float sbi[192];
    __shared__ float rbfT[64 * 68];   // [k][edge], pad 68
    __shared__ float sgeom[64 * 8];
    __shared__ float sud[64 * 3];
    __shared__ int sii[64];
    __shared__ int sjj[64];

    int t = threadIdx.x;
    for (int p = t; p < 64 * 192; p += TPB) sW[p] = W_edge[p];
    for (int p = t; p < 8 * 192; p += TPB) sWinv[p] = W_inv[p];
    if (t < 192) { sbe[t] = b_edge[t]; sbi[t] = b_inv[t]; }

    int oc = t & 31;
    int er = t >> 5;  // 0..7
    const float inv_sqrt3 = 0.57735026918962584f;
    const float inv_sqrt_h = 0.125f;

    int ntiles = (E + TILE_E - 1) / TILE_E;
    for (int tile = blockIdx.x; tile < ntiles; tile += gridDim.x) {
        int e0 = tile * TILE_E;
        __syncthreads();   // previous epilogue done before restage
        if (t < 64) {
            int rg = e0 + t;
            sjj[t] = (rg < E) ? jj_s[rg] : 0;
            sii[t] = (rg < E) ? ii_s[rg] : -1;
        }
        for (int p = t; p < 64 * 8; p += TPB)
            sgeom[p] = (e0 + (p >> 3) < E) ? geom_s[(size_t)e0 * 8 + p] : 0.f;
        for (int p = t; p < 64 * 3; p += TPB)
            sud[p] = (e0 + p / 3 < E) ? ud_s[(size_t)e0 * 3 + p] : 0.f;
        {
            int w = t >> 6, l = t & 63;
#pragma unroll
            for (int p = 0; p < 16; ++p) {
                int r = w + 4 * p;
                int rg = e0 + r;
                float v = 0.f;
                if (rg < E) {
                    int eg = perm[rg];       // uniform per wave -> broadcast load
                    v = rbf[(size_t)eg * 64 + l];
                }
                rbfT[l * 68 + r] = v;
            }
        }
        __syncthreads();

        float acc[8][6];
#pragma unroll
        for (int e = 0; e < 8; ++e)
#pragma unroll
            for (int m = 0; m < 6; ++m) acc[e][m] = 0.f;

        const float* rb = &rbfT[er * 8];
#pragma unroll 4
        for (int k = 0; k < 64; ++k) {
            float4 r0 = *(const float4*)&rb[k * 68];
            float4 r1 = *(const float4*)&rb[k * 68 + 4];
            float wv[6];
#pragma unroll
            for (int m = 0; m < 6; ++m) wv[m] = sW[k * 192 + oc + 32 * m];
            float re[8] = {r0.x, r0.y, r0.z, r0.w, r1.x, r1.y, r1.z, r1.w};
#pragma unroll
            for (int e = 0; e < 8; ++e)
#pragma unroll
                for (int m = 0; m < 6; ++m)
                    acc[e][m] = fmaf(re[e], wv[m], acc[e][m]);
        }

        // ---- epilogue with run accumulation over same-i edges ----
        float a_s0 = 0.f, a_s1 = 0.f;
        float a_v[3][2] = {{0.f, 0.f}, {0.f, 0.f}, {0.f, 0.f}};
        int runi = -1;
        bool any = false;
#pragma unroll 1
        for (int e = 0; e < 8; ++e) {
            int el = er * 8 + e;
            int rg = e0 + el;
            if (rg >= E) break;
            int j = sjj[el], i = sii[el];
            if (i != runi) {
                if (any) {
                    atomicAdd(&dscal[(size_t)runi * 64 + oc], a_s0);
                    atomicAdd(&dscal[(size_t)runi * 64 + oc + 32], a_s1);
#pragma unroll
                    for (int d = 0; d < 3; ++d) {
                        atomicAdd(&dvec[(size_t)runi * 192 + d * 64 + oc], a_v[d][0]);
                        atomicAdd(&dvec[(size_t)runi * 192 + d * 64 + oc + 32], a_v[d][1]);
                    }
                }
                a_s0 = 0.f; a_s1 = 0.f;
#pragma unroll
                for (int d = 0; d < 3; ++d) { a_v[d][0] = 0.f; a_v[d][1] = 0.f; }
                runi = i;
            }
            any = true;
            float x[6];
#pragma unroll
            for (int m = 0; m < 6; ++m) {
                int o = oc + 32 * m;
                float u = sbi[o];
#pragma unroll
                for (int c = 0; c < 8; ++c)
                    u = fmaf(sgeom[el * 8 + c], sWinv[c * 192 + o], u);
                float sig = 1.0f / (1.0f + __expf(-u));
                float v = u * sig * (1.0f / 0.6f);
                v = fminf(fmaxf(v, -20.f), 20.f);
                float e2v = __expf(2.0f * v);
                float gate = (e2v - 1.0f) / (e2v + 1.0f);
                float rh = (acc[e][m] + sbe[o]) * (1.0f + gate);
                x[m] = sproj[(size_t)j * 192 + o] * rh * inv_sqrt3;
            }
            a_s0 += x[4];
            a_s1 += x[5];
            float udv[3] = {sud[el * 3], sud[el * 3 + 1], sud[el * 3 + 2]};
            const float* nv = &nvec[(size_t)j * 192];
#pragma unroll
            for (int d = 0; d < 3; ++d) {
                a_v[d][0] += (x[0] * nv[d * 64 + oc] + x[2] * udv[d]) * inv_sqrt_h;
                a_v[d][1] += (x[1] * nv[d * 64 + oc + 32] + x[3] * udv[d]) * inv_sqrt_h;
            }
        }
        if (any) {
            atomicAdd(&dscal[(size_t)runi * 64 + oc], a_s0);
            atomicAdd(&dscal[(size_t)runi * 64 + oc + 32], a_s1);
#pragma unroll
            for (int d = 0; d < 3; ++d) {
                atomicAdd(&dvec[(size_t)runi * 192 + d * 64 + oc], a_v[d][0]);
                atomicAdd(&dvec[(size_t)runi * 192 + d * 64 + oc + 32], a_v[d][1]);
            }
        }
    }
}

// ---------------------------------------------------------------------------
extern "C" void kernel_launch(void* const* d_in, const int* in_sizes, int n_in,
                              void* d_out, int out_size, void* d_ws, size_t ws_size,
                              hipStream_t stream) {
    const float* node_scalar = (const float*)d_in[0];
    const float* node_vector = (const float*)d_in[1];
    const float* edge_rbf    = (const float*)d_in[2];
    const float* edge_udiff  = (const float*)d_in[3];
    const int*   edge_index  = (const int*)d_in[4];
    const float* W_edge      = (const float*)d_in[5];
    const float* b_edge      = (const float*)d_in[6];
    const float* W_x1        = (const float*)d_in[7];
    const float* b_x1        = (const float*)d_in[8];
    const float* W_x2        = (const float*)d_in[9];
    const float* b_x2        = (const float*)d_in[10];
    const float* ln_g        = (const float*)d_in[11];
    const float* ln_b        = (const float*)d_in[12];
    const float* W_inv       = (const float*)d_in[13];
    const float* b_inv       = (const float*)d_in[14];

    int N = in_sizes[0] / 64;
    int E = in_sizes[3] / 3;

    float* ws = (float*)d_ws;
    size_t o = 0;
    float* ref_acc = ws + o; o += (size_t)N * 3;    // 3N
    int*   icnt    = (int*)(ws + o); o += N;        // N   (contiguous w/ ref_acc for 1 memset)
    int*   offs    = (int*)(ws + o); o += N;
    int*   cursor  = (int*)(ws + o); o += N;
    int*   bsum    = (int*)(ws + o); o += 1024;
    float* ref_vec = ws + o; o += (size_t)N * 3;
    float* ref_sh  = ws + o; o += (size_t)N * SH49;
    float* sproj   = ws + o; o += (size_t)N * 192;
    int*   perm    = (int*)(ws + o); o += E;
    float* geom_s  = ws + o; o += (size_t)E * 8;
    float* ud_s    = ws + o; o += (size_t)E * 3;
    int*   ii_s    = (int*)(ws + o); o += E;
    int*   jj_s    = (int*)(ws + o); o += E;

    float* dscal = (float*)d_out;                       // N*64
    float* dvec  = (float*)d_out + (size_t)N * 64;      // N*192

    hipMemsetAsync(ref_acc, 0, (size_t)N * 4 * sizeof(float), stream);
    hipMemsetAsync(d_out, 0, (size_t)out_size * sizeof(float), stream);

    int nb = (N + SCB - 1) / SCB;

    k_scatter_ref<<<(E + TPB - 1) / TPB, TPB, 0, stream>>>(edge_udiff, edge_index,
                                                           ref_acc, icnt, E);
    k_node_ref<<<(N + TPB - 1) / TPB, TPB, 0, stream>>>(ref_acc, icnt, ref_vec,
                                                        ref_sh, N);
    k_scan1<<<nb, SCB, 0, stream>>>(icnt, offs, bsum, N);
    k_scan2<<<1, 1024, 0, stream>>>(bsum, nb);
    k_scan3<<<nb, SCB, 0, stream>>>(offs, bsum, cursor, N);
    k_perm<<<(E + TPB - 1) / TPB, TPB, 0, stream>>>(edge_index, cursor, perm, E);
    k_sproj<<<512, TPB, 0, stream>>>(node_scalar, W_x1, b_x1, W_x2, b_x2, sproj, N);
    k_geom_s<<<(E + TPB - 1) / TPB, TPB, 0, stream>>>(perm, edge_udiff, edge_index,
                                                      ref_vec, ref_sh, ln_g, ln_b,
                                                      geom_s, ud_s, ii_s, jj_s, E);
    k_main<<<512, TPB, 0, stream>>>(edge_rbf, W_edge, b_edge, W_inv, b_inv, geom_s,
                                    sproj, node_vector, ud_s, ii_s, jj_s, perm,
                                    dscal, dvec, E);
}